// Round 2
// baseline (1233.599 us; speedup 1.0000x reference)
//
#include <hip/hip_runtime.h>
#include <hip/hip_bf16.h>
#include <stdint.h>

// Problem constants: B=2, L=2048, D=4096, H=32, KVH=8, HD=128, REP=4
// Pipeline (all bf16 MFMA, fp32 accum):
//   cast x -> bf16; cast+transpose wq|wk|wv -> Wt[6144][4096]; wo -> Wot[4096][4096]
//   QKV GEMM (bf16 out, staged in d_out)
//   RoPE(Q,K) -> head-major bf16; V -> transposed bf16
//   flash-style causal GQA attention
//   output GEMM (fp32 out -> d_out)
// Workspace budget: 112 MB of d_ws + d_out used as staging for cqkv.

typedef __attribute__((ext_vector_type(8))) short short8;
typedef __attribute__((ext_vector_type(4))) float floatx4;

__device__ __forceinline__ unsigned short f2bf(float f) {
    union { float f; uint32_t u; } v; v.f = f;
    uint32_t u = v.u;
    return (unsigned short)((u + 0x7fffu + ((u >> 16) & 1u)) >> 16);
}

__device__ __forceinline__ float bf2f(unsigned short h) {
    union { uint32_t u; float f; } v; v.u = (uint32_t)h << 16; return v.f;
}

// Async global->LDS, 16B per lane. LDS dest must be wave-uniform base + lane*16.
__device__ __forceinline__ void g2l16(const void* g, void* l) {
    __builtin_amdgcn_global_load_lds(
        (__attribute__((address_space(1))) void*)g,
        (__attribute__((address_space(3))) void*)l,
        16, 0, 0);
}

// ---------------- cast x (fp32 -> bf16, row-major) ----------------
__global__ __launch_bounds__(256) void cast_x_kernel(const float* __restrict__ X,
                                                     unsigned short* __restrict__ Xb,
                                                     int n4) {
    int i = blockIdx.x * 256 + threadIdx.x;
    if (i < n4) {
        floatx4 v = *(const floatx4*)&X[i * 4];
        unsigned int p0 = (unsigned int)f2bf(v[0]) | ((unsigned int)f2bf(v[1]) << 16);
        unsigned int p1 = (unsigned int)f2bf(v[2]) | ((unsigned int)f2bf(v[3]) << 16);
        uint2 pv; pv.x = p0; pv.y = p1;
        *(uint2*)&Xb[i * 4] = pv;
    }
}

// ------------- cast+transpose weight: W[K=4096][N] fp32 -> Wt[rowoff+n][4096] bf16 -------------
__global__ __launch_bounds__(256) void cast_transpose_kernel(const float* __restrict__ W,
                                                             unsigned short* __restrict__ Wt,
                                                             int N, int rowoff) {
    __shared__ alignas(16) float T[64][65];
    int n0 = blockIdx.x * 64, k0 = blockIdx.y * 64;
    int tid = threadIdx.x;
#pragma unroll
    for (int i = 0; i < 16; ++i) {
        int idx = i * 256 + tid;
        int r = idx >> 6, c = idx & 63;   // r: k-dir, c: n-dir
        T[r][c] = W[(k0 + r) * N + n0 + c];
    }
    __syncthreads();
#pragma unroll
    for (int i = 0; i < 16; ++i) {
        int idx = i * 256 + tid;
        int rn = idx >> 6, ck = idx & 63;
        Wt[(size_t)(rowoff + n0 + rn) * 4096 + k0 + ck] = f2bf(T[ck][rn]);
    }
}

// ---------------- GEMM: C[M][N] = A[M][K] bf16 * Bt[N][K] bf16 ----------------
// 128x128 tile, BK=32, 256 threads (2x2 waves of 64x64), m97-style.
template<bool BF16OUT>
__global__ __launch_bounds__(256) void gemm_bt_kernel(const unsigned short* __restrict__ A,
                                                      const unsigned short* __restrict__ Bt,
                                                      float* __restrict__ Cf,
                                                      unsigned short* __restrict__ Cb,
                                                      int M, int N, int K) {
    __shared__ alignas(16) unsigned short As[128 * 32];
    __shared__ alignas(16) unsigned short Bs[128 * 32];
    const int tid = threadIdx.x;
    const int n0 = blockIdx.x * 128;
    const int m0 = blockIdx.y * 128;
    const int w = tid >> 6, lane = tid & 63, lr = lane & 15, lg = lane >> 4;
    const int wm = (w >> 1) * 64, wn = (w & 1) * 64;

    floatx4 acc[4][4];
#pragma unroll
    for (int i = 0; i < 4; ++i)
#pragma unroll
        for (int j = 0; j < 4; ++j)
            acc[i][j] = (floatx4){0.f, 0.f, 0.f, 0.f};

    const unsigned short* ag = A + (size_t)(m0 + (tid >> 2)) * K + (tid & 3) * 8;
    const unsigned short* bg = Bt + (size_t)(n0 + (tid >> 2)) * K + (tid & 3) * 8;
    const size_t half = (size_t)64 * K;

    for (int k0 = 0; k0 < K; k0 += 32) {
        __syncthreads();   // protect LDS from previous iteration's readers
        g2l16(ag + k0,        &As[tid * 8]);
        g2l16(ag + k0 + half, &As[2048 + tid * 8]);
        g2l16(bg + k0,        &Bs[tid * 8]);
        g2l16(bg + k0 + half, &Bs[2048 + tid * 8]);
        __syncthreads();   // compiler drains vmcnt before barrier

        short8 a[4], b[4];
#pragma unroll
        for (int mt = 0; mt < 4; ++mt)
            a[mt] = *(const short8*)&As[(wm + mt * 16 + lr) * 32 + lg * 8];
#pragma unroll
        for (int nt = 0; nt < 4; ++nt)
            b[nt] = *(const short8*)&Bs[(wn + nt * 16 + lr) * 32 + lg * 8];
#pragma unroll
        for (int mt = 0; mt < 4; ++mt)
#pragma unroll
            for (int nt = 0; nt < 4; ++nt)
                acc[mt][nt] = __builtin_amdgcn_mfma_f32_16x16x32_bf16(a[mt], b[nt], acc[mt][nt], 0, 0, 0);
    }

    // Epilogue: C/D layout row=(lane>>4)*4+reg, col=lane&15
#pragma unroll
    for (int mt = 0; mt < 4; ++mt)
#pragma unroll
        for (int nt = 0; nt < 4; ++nt)
#pragma unroll
            for (int r = 0; r < 4; ++r) {
                size_t idx = (size_t)(m0 + wm + mt * 16 + lg * 4 + r) * N + n0 + wn + nt * 16 + lr;
                if (BF16OUT) Cb[idx] = f2bf(acc[mt][nt][r]);
                else         Cf[idx] = acc[mt][nt][r];
            }
}

// ---------------- RoPE on Q and K slices of Cqkv (bf16) -> bf16 head-major layouts ----------------
// Q pre-scaled by 1/sqrt(HD).
__global__ __launch_bounds__(256) void rope_qk_kernel(const unsigned short* __restrict__ Cqkv,
                                                      const float* __restrict__ fc,
                                                      const float* __restrict__ fs,
                                                      unsigned short* __restrict__ Qb,
                                                      unsigned short* __restrict__ Kb) {
    int e = blockIdx.x * 256 + threadIdx.x;   // 0..2559
    int t = blockIdx.y;                       // token
    int b = t >> 11, l = t & 2047;
    if (e < 2048) {
        int h = e >> 6, d2 = e & 63;
        unsigned int xv = *(const unsigned int*)&Cqkv[(size_t)t * 6144 + h * 128 + d2 * 2];
        float xr = bf2f((unsigned short)(xv & 0xffffu));
        float xi = bf2f((unsigned short)(xv >> 16));
        float c = fc[l * 64 + d2], s = fs[l * 64 + d2];
        const float sc = 0.08838834764831845f;  // 1/sqrt(128)
        float orr = (xr * c - xi * s) * sc;
        float oii = (xr * s + xi * c) * sc;
        unsigned int pack = (unsigned int)f2bf(orr) | ((unsigned int)f2bf(oii) << 16);
        *(unsigned int*)&Qb[(size_t)((b * 32 + h) * 2048 + l) * 128 + d2 * 2] = pack;
    } else {
        int e2 = e - 2048;
        int kvh = e2 >> 6, d2 = e2 & 63;
        unsigned int xv = *(const unsigned int*)&Cqkv[(size_t)t * 6144 + 4096 + kvh * 128 + d2 * 2];
        float xr = bf2f((unsigned short)(xv & 0xffffu));
        float xi = bf2f((unsigned short)(xv >> 16));
        float c = fc[l * 64 + d2], s = fs[l * 64 + d2];
        float orr = xr * c - xi * s;
        float oii = xr * s + xi * c;
        unsigned int pack = (unsigned int)f2bf(orr) | ((unsigned int)f2bf(oii) << 16);
        *(unsigned int*)&Kb[(size_t)((b * 8 + kvh) * 2048 + l) * 128 + d2 * 2] = pack;
    }
}

// ---------------- V slice of Cqkv (bf16) -> transposed bf16 Vt[b][kvh][128][2048] ----------------
__global__ __launch_bounds__(256) void transpose_v_kernel(const unsigned short* __restrict__ Cqkv,
                                                          unsigned short* __restrict__ Vt) {
    __shared__ unsigned short T[64][130];   // pad 130: row stride 65 dwords -> <=2-way bank aliasing
    int l0 = blockIdx.x * 64;
    int kvh = blockIdx.y;
    int b = blockIdx.z;
    int tid = threadIdx.x;
#pragma unroll
    for (int i = 0; i < 32; ++i) {
        int idx = i * 256 + tid;
        int r = idx >> 7, c = idx & 127;
        T[r][c] = Cqkv[(size_t)(b * 2048 + l0 + r) * 6144 + 5120 + kvh * 128 + c];
    }
    __syncthreads();
#pragma unroll
    for (int i = 0; i < 32; ++i) {
        int idx = i * 256 + tid;
        int d = idx >> 6, lx = idx & 63;
        Vt[((size_t)(b * 8 + kvh) * 128 + d) * 2048 + l0 + lx] = T[lx][d];
    }
}

// ---------------- Flash-style causal attention ----------------
// grid (L/64, H, B), 256 threads. Wave w handles q rows [q0+16w, q0+16w+16).
__global__ __launch_bounds__(256) void attn_kernel(const unsigned short* __restrict__ Qb,
                                                   const unsigned short* __restrict__ Kb,
                                                   const unsigned short* __restrict__ Vt,
                                                   unsigned short* __restrict__ AO) {
    __shared__ alignas(16) unsigned short K_lds[64 * 128];   // [key][dim]
    __shared__ alignas(16) unsigned short V_lds[128 * 64];   // [dim][key]
    __shared__ alignas(16) unsigned short P_lds[4][16 * 64]; // per-wave [qrow][key]

    const int tid = threadIdx.x;
    const int qt = blockIdx.x, h = blockIdx.y, b = blockIdx.z;
    const int kvh = h >> 2;
    const int q0 = qt * 64;
    const int w = tid >> 6, lane = tid & 63, lr = lane & 15, lg = lane >> 4;

    const unsigned short* Q  = Qb + (size_t)((b * 32 + h) * 2048) * 128;
    const unsigned short* Kp = Kb + (size_t)((b * 8 + kvh) * 2048) * 128;
    const unsigned short* Vp = Vt + (size_t)((b * 8 + kvh) * 128) * 2048;

    // Q a-frags: A[m=lane&15][k=quad*8+j], 4 frags cover k=0..127
    short8 qa[4];
#pragma unroll
    for (int f = 0; f < 4; ++f)
        qa[f] = *(const short8*)&Q[(q0 + w * 16 + lr) * 128 + f * 32 + lg * 8];

    float m_i[4], l_i[4];
    floatx4 o[8];
#pragma unroll
    for (int r = 0; r < 4; ++r) { m_i[r] = -1e30f; l_i[r] = 0.f; }
#pragma unroll
    for (int dt = 0; dt < 8; ++dt) o[dt] = (floatx4){0.f, 0.f, 0.f, 0.f};

    for (int it = 0; it <= qt; ++it) {
        const int k0 = it * 64;
        __syncthreads();   // prior iteration's LDS readers done
#pragma unroll
        for (int i = 0; i < 4; ++i) {
            g2l16(&Kp[(k0 + i * 16 + (tid >> 4)) * 128 + (tid & 15) * 8], &K_lds[i * 2048 + tid * 8]);
            g2l16(&Vp[(i * 32 + (tid >> 3)) * 2048 + k0 + (tid & 7) * 8],  &V_lds[i * 2048 + tid * 8]);
        }
        __syncthreads();   // staging visible

        // S = Q * K^T  (16 q-rows x 64 keys per wave)
        floatx4 s[4];
#pragma unroll
        for (int nt = 0; nt < 4; ++nt) s[nt] = (floatx4){0.f, 0.f, 0.f, 0.f};
#pragma unroll
        for (int nt = 0; nt < 4; ++nt)
#pragma unroll
            for (int f = 0; f < 4; ++f) {
                short8 kb = *(const short8*)&K_lds[(nt * 16 + lr) * 128 + f * 32 + lg * 8];
                s[nt] = __builtin_amdgcn_mfma_f32_16x16x32_bf16(qa[f], kb, s[nt], 0, 0, 0);
            }

        if (it == qt) {
            // diagonal tile: mask col_local > row_local
#pragma unroll
            for (int nt = 0; nt < 4; ++nt)
#pragma unroll
                for (int r = 0; r < 4; ++r)
                    if (nt * 16 + lr > w * 16 + lg * 4 + r) s[nt][r] = -1e30f;
        }

        // online softmax (rows owned by 16-lane groups; reduce across lr)
        float mx[4];
#pragma unroll
        for (int r = 0; r < 4; ++r)
            mx[r] = fmaxf(fmaxf(s[0][r], s[1][r]), fmaxf(s[2][r], s[3][r]));
#pragma unroll
        for (int off = 1; off < 16; off <<= 1)
#pragma unroll
            for (int r = 0; r < 4; ++r)
                mx[r] = fmaxf(mx[r], __shfl_xor(mx[r], off, 64));

        float al[4], rs[4], p[4][4];
#pragma unroll
        for (int r = 0; r < 4; ++r) {
            float mn = fmaxf(m_i[r], mx[r]);
            al[r] = __expf(m_i[r] - mn);
            m_i[r] = mn;
            rs[r] = 0.f;
        }
#pragma unroll
        for (int nt = 0; nt < 4; ++nt)
#pragma unroll
            for (int r = 0; r < 4; ++r) {
                p[nt][r] = __expf(s[nt][r] - m_i[r]);
                rs[r] += p[nt][r];
            }
#pragma unroll
        for (int off = 1; off < 16; off <<= 1)
#pragma unroll
            for (int r = 0; r < 4; ++r)
                rs[r] += __shfl_xor(rs[r], off, 64);
#pragma unroll
        for (int r = 0; r < 4; ++r) l_i[r] = l_i[r] * al[r] + rs[r];
#pragma unroll
        for (int dt = 0; dt < 8; ++dt)
#pragma unroll
            for (int r = 0; r < 4; ++r) o[dt][r] *= al[r];

        // P: C-layout -> LDS -> A-layout (per-wave region)
#pragma unroll
        for (int nt = 0; nt < 4; ++nt)
#pragma unroll
            for (int r = 0; r < 4; ++r)
                P_lds[w][(lg * 4 + r) * 64 + nt * 16 + lr] = f2bf(p[nt][r]);
        __syncthreads();   // conservative: P writes visible before frag reads

        // O += P * V
#pragma unroll
        for (int kk = 0; kk < 2; ++kk) {
            short8 pa = *(const short8*)&P_lds[w][lr * 64 + kk * 32 + lg * 8];
#pragma unroll
            for (int dt = 0; dt < 8; ++dt) {
                short8 vb = *(const short8*)&V_lds[(dt * 16 + lr) * 64 + kk * 32 + lg * 8];
                o[dt] = __builtin_amdgcn_mfma_f32_16x16x32_bf16(pa, vb, o[dt], 0, 0, 0);
            }
        }
    }

    // epilogue: normalize, write AO[token][h*128+d] bf16
#pragma unroll
    for (int dt = 0; dt < 8; ++dt)
#pragma unroll
        for (int r = 0; r < 4; ++r) {
            int q = q0 + w * 16 + lg * 4 + r;
            AO[(size_t)(b * 2048 + q) * 4096 + h * 128 + dt * 16 + lr] = f2bf(o[dt][r] / l_i[r]);
        }
}

extern "C" void kernel_launch(void* const* d_in, const int* in_sizes, int n_in,
                              void* d_out, int out_size, void* d_ws, size_t ws_size,
                              hipStream_t stream) {
    const float* x  = (const float*)d_in[0];
    const float* wq = (const float*)d_in[1];
    const float* wk = (const float*)d_in[2];
    const float* wv = (const float*)d_in[3];
    const float* wo = (const float*)d_in[4];
    const float* fc = (const float*)d_in[5];
    const float* fs = (const float*)d_in[6];
    float* out = (float*)d_out;

    // ---- workspace layout (112 MB total) ----
    // [0, 50.3MB):      wqkvt   -- dead after gemm1, then reused as qb|kb|vt
    // [50.3, 83.9MB):   xb      -- dead after gemm1, then reused as ao
    // [83.9, 117.4MB):  wot
    // cqkv (bf16, 50.3MB) staged in d_out (67MB), consumed before final GEMM writes it.
    char* ws = (char*)d_ws;
    unsigned short* wqkvt = (unsigned short*)(ws);
    unsigned short* qb    = (unsigned short*)(ws);                      // alias wqkvt
    unsigned short* kb    = (unsigned short*)(ws + 33554432);           // alias wqkvt+33.5MB
    unsigned short* vt    = (unsigned short*)(ws + 41943040);           // alias wqkvt+41.9MB
    unsigned short* xb    = (unsigned short*)(ws + 50331648);
    unsigned short* ao    = xb;                                          // alias xb
    unsigned short* wot   = (unsigned short*)(ws + 83886080);
    unsigned short* cqkv  = (unsigned short*)d_out;                      // staging in d_out

    cast_x_kernel<<<16384, 256, 0, stream>>>(x, xb, 4194304);
    cast_transpose_kernel<<<dim3(64, 64), 256, 0, stream>>>(wq, wqkvt, 4096, 0);
    cast_transpose_kernel<<<dim3(16, 64), 256, 0, stream>>>(wk, wqkvt, 1024, 4096);
    cast_transpose_kernel<<<dim3(16, 64), 256, 0, stream>>>(wv, wqkvt, 1024, 5120);
    cast_transpose_kernel<<<dim3(64, 64), 256, 0, stream>>>(wo, wot, 4096, 0);

    // QKV GEMM: [4096,4096] x [6144,4096]^T -> cqkv bf16 (in d_out)
    gemm_bt_kernel<true><<<dim3(48, 32), 256, 0, stream>>>(xb, wqkvt, nullptr, cqkv, 4096, 6144, 4096);

    // RoPE + layouts (overwrite wqkvt region -- gemm1 already consumed it)
    rope_qk_kernel<<<dim3(10, 4096), 256, 0, stream>>>(cqkv, fc, fs, qb, kb);
    transpose_v_kernel<<<dim3(32, 8, 2), 256, 0, stream>>>(cqkv, vt);

    // attention -> ao (overwrites xb)
    attn_kernel<<<dim3(32, 32, 2), 256, 0, stream>>>(qb, kb, vt, ao);

    // output GEMM: [4096,4096] x [4096,4096]^T -> out fp32 (overwrites cqkv staging)
    gemm_bt_kernel<false><<<dim3(32, 32), 256, 0, stream>>>(ao, wot, out, nullptr, 4096, 4096, 4096);
}

// Round 3
// 1008.034 us; speedup vs baseline: 1.2238x; 1.2238x over previous
//
#include <hip/hip_runtime.h>
#include <hip/hip_bf16.h>
#include <stdint.h>

// Problem constants: B=2, L=2048, D=4096, H=32, KVH=8, HD=128, REP=4
// Pipeline (all bf16 MFMA, fp32 accum):
//   cast x -> bf16; cast+transpose wq|wk|wv -> Wt[6144][4096]; wo -> Wot[4096][4096]
//   QKV GEMM (bf16 out, staged in d_out)
//   RoPE(Q,K) -> head-major bf16 (Q pre-scaled by log2(e)/sqrt(HD)); V -> transposed bf16
//   flash-style causal GQA attention (exp2 domain, XOR-swizzled LDS)
//   output GEMM (fp32 out -> d_out)

typedef __attribute__((ext_vector_type(8))) short short8;
typedef __attribute__((ext_vector_type(4))) float floatx4;

__device__ __forceinline__ unsigned short f2bf(float f) {
    union { float f; uint32_t u; } v; v.f = f;
    uint32_t u = v.u;
    return (unsigned short)((u + 0x7fffu + ((u >> 16) & 1u)) >> 16);
}

__device__ __forceinline__ float bf2f(unsigned short h) {
    union { uint32_t u; float f; } v; v.u = (uint32_t)h << 16; return v.f;
}

// Async global->LDS, 16B per lane. LDS dest must be wave-uniform base + lane*16.
__device__ __forceinline__ void g2l16(const void* g, void* l) {
    __builtin_amdgcn_global_load_lds(
        (__attribute__((address_space(1))) void*)g,
        (__attribute__((address_space(3))) void*)l,
        16, 0, 0);
}

// ---------------- cast x (fp32 -> bf16, row-major) ----------------
__global__ __launch_bounds__(256) void cast_x_kernel(const float* __restrict__ X,
                                                     unsigned short* __restrict__ Xb,
                                                     int n4) {
    int i = blockIdx.x * 256 + threadIdx.x;
    if (i < n4) {
        floatx4 v = *(const floatx4*)&X[i * 4];
        unsigned int p0 = (unsigned int)f2bf(v[0]) | ((unsigned int)f2bf(v[1]) << 16);
        unsigned int p1 = (unsigned int)f2bf(v[2]) | ((unsigned int)f2bf(v[3]) << 16);
        uint2 pv; pv.x = p0; pv.y = p1;
        *(uint2*)&Xb[i * 4] = pv;
    }
}

// ------------- cast+transpose weight: W[K=4096][N] fp32 -> Wt[rowoff+n][4096] bf16 -------------
__global__ __launch_bounds__(256) void cast_transpose_kernel(const float* __restrict__ W,
                                                             unsigned short* __restrict__ Wt,
                                                             int N, int rowoff) {
    __shared__ alignas(16) float T[64][65];
    int n0 = blockIdx.x * 64, k0 = blockIdx.y * 64;
    int tid = threadIdx.x;
#pragma unroll
    for (int i = 0; i < 16; ++i) {
        int idx = i * 256 + tid;
        int r = idx >> 6, c = idx & 63;   // r: k-dir, c: n-dir
        T[r][c] = W[(k0 + r) * N + n0 + c];
    }
    __syncthreads();
#pragma unroll
    for (int i = 0; i < 16; ++i) {
        int idx = i * 256 + tid;
        int rn = idx >> 6, ck = idx & 63;
        Wt[(size_t)(rowoff + n0 + rn) * 4096 + k0 + ck] = f2bf(T[ck][rn]);
    }
}

// ---------------- GEMM: C[M][N] = A[M][K] bf16 * Bt[N][K] bf16 ----------------
// 128x128 tile, BK=32, 256 threads (2x2 waves of 64x64), m97-style.
template<bool BF16OUT>
__global__ __launch_bounds__(256) void gemm_bt_kernel(const unsigned short* __restrict__ A,
                                                      const unsigned short* __restrict__ Bt,
                                                      float* __restrict__ Cf,
                                                      unsigned short* __restrict__ Cb,
                                                      int M, int N, int K) {
    __shared__ alignas(16) unsigned short As[128 * 32];
    __shared__ alignas(16) unsigned short Bs[128 * 32];
    const int tid = threadIdx.x;
    const int n0 = blockIdx.x * 128;
    const int m0 = blockIdx.y * 128;
    const int w = tid >> 6, lane = tid & 63, lr = lane & 15, lg = lane >> 4;
    const int wm = (w >> 1) * 64, wn = (w & 1) * 64;

    floatx4 acc[4][4];
#pragma unroll
    for (int i = 0; i < 4; ++i)
#pragma unroll
        for (int j = 0; j < 4; ++j)
            acc[i][j] = (floatx4){0.f, 0.f, 0.f, 0.f};

    const unsigned short* ag = A + (size_t)(m0 + (tid >> 2)) * K + (tid & 3) * 8;
    const unsigned short* bg = Bt + (size_t)(n0 + (tid >> 2)) * K + (tid & 3) * 8;
    const size_t half = (size_t)64 * K;

    for (int k0 = 0; k0 < K; k0 += 32) {
        __syncthreads();   // protect LDS from previous iteration's readers
        g2l16(ag + k0,        &As[tid * 8]);
        g2l16(ag + k0 + half, &As[2048 + tid * 8]);
        g2l16(bg + k0,        &Bs[tid * 8]);
        g2l16(bg + k0 + half, &Bs[2048 + tid * 8]);
        __syncthreads();   // compiler drains vmcnt before barrier

        short8 a[4], b[4];
#pragma unroll
        for (int mt = 0; mt < 4; ++mt)
            a[mt] = *(const short8*)&As[(wm + mt * 16 + lr) * 32 + lg * 8];
#pragma unroll
        for (int nt = 0; nt < 4; ++nt)
            b[nt] = *(const short8*)&Bs[(wn + nt * 16 + lr) * 32 + lg * 8];
#pragma unroll
        for (int mt = 0; mt < 4; ++mt)
#pragma unroll
            for (int nt = 0; nt < 4; ++nt)
                acc[mt][nt] = __builtin_amdgcn_mfma_f32_16x16x32_bf16(a[mt], b[nt], acc[mt][nt], 0, 0, 0);
    }

    // Epilogue: C/D layout row=(lane>>4)*4+reg, col=lane&15
#pragma unroll
    for (int mt = 0; mt < 4; ++mt)
#pragma unroll
        for (int nt = 0; nt < 4; ++nt)
#pragma unroll
            for (int r = 0; r < 4; ++r) {
                size_t idx = (size_t)(m0 + wm + mt * 16 + lg * 4 + r) * N + n0 + wn + nt * 16 + lr;
                if (BF16OUT) Cb[idx] = f2bf(acc[mt][nt][r]);
                else         Cf[idx] = acc[mt][nt][r];
            }
}

// ---------------- RoPE on Q and K slices of Cqkv (bf16) -> bf16 head-major layouts ----------------
// Q pre-scaled by log2(e)/sqrt(HD) so attention works in exp2 domain.
__global__ __launch_bounds__(256) void rope_qk_kernel(const unsigned short* __restrict__ Cqkv,
                                                      const float* __restrict__ fc,
                                                      const float* __restrict__ fs,
                                                      unsigned short* __restrict__ Qb,
                                                      unsigned short* __restrict__ Kb) {
    int e = blockIdx.x * 256 + threadIdx.x;   // 0..2559
    int t = blockIdx.y;                       // token
    int b = t >> 11, l = t & 2047;
    if (e < 2048) {
        int h = e >> 6, d2 = e & 63;
        unsigned int xv = *(const unsigned int*)&Cqkv[(size_t)t * 6144 + h * 128 + d2 * 2];
        float xr = bf2f((unsigned short)(xv & 0xffffu));
        float xi = bf2f((unsigned short)(xv >> 16));
        float c = fc[l * 64 + d2], s = fs[l * 64 + d2];
        const float sc = 1.4426950408889634f * 0.08838834764831845f;  // log2(e)/sqrt(128)
        float orr = (xr * c - xi * s) * sc;
        float oii = (xr * s + xi * c) * sc;
        unsigned int pack = (unsigned int)f2bf(orr) | ((unsigned int)f2bf(oii) << 16);
        *(unsigned int*)&Qb[(size_t)((b * 32 + h) * 2048 + l) * 128 + d2 * 2] = pack;
    } else {
        int e2 = e - 2048;
        int kvh = e2 >> 6, d2 = e2 & 63;
        unsigned int xv = *(const unsigned int*)&Cqkv[(size_t)t * 6144 + 4096 + kvh * 128 + d2 * 2];
        float xr = bf2f((unsigned short)(xv & 0xffffu));
        float xi = bf2f((unsigned short)(xv >> 16));
        float c = fc[l * 64 + d2], s = fs[l * 64 + d2];
        float orr = xr * c - xi * s;
        float oii = xr * s + xi * c;
        unsigned int pack = (unsigned int)f2bf(orr) | ((unsigned int)f2bf(oii) << 16);
        *(unsigned int*)&Kb[(size_t)((b * 8 + kvh) * 2048 + l) * 128 + d2 * 2] = pack;
    }
}

// ---------------- V slice of Cqkv (bf16) -> transposed bf16 Vt[b][kvh][128][2048] ----------------
__global__ __launch_bounds__(256) void transpose_v_kernel(const unsigned short* __restrict__ Cqkv,
                                                          unsigned short* __restrict__ Vt) {
    __shared__ unsigned short T[64][130];
    int l0 = blockIdx.x * 64;
    int kvh = blockIdx.y;
    int b = blockIdx.z;
    int tid = threadIdx.x;
#pragma unroll
    for (int i = 0; i < 32; ++i) {
        int idx = i * 256 + tid;
        int r = idx >> 7, c = idx & 127;
        T[r][c] = Cqkv[(size_t)(b * 2048 + l0 + r) * 6144 + 5120 + kvh * 128 + c];
    }
    __syncthreads();
#pragma unroll
    for (int i = 0; i < 32; ++i) {
        int idx = i * 256 + tid;
        int d = idx >> 6, lx = idx & 63;
        Vt[((size_t)(b * 8 + kvh) * 128 + d) * 2048 + l0 + lx] = T[lx][d];
    }
}

// ---------------- Flash-style causal attention ----------------
// grid (L/64, H, B), 256 threads. Wave w handles q rows [q0+16w, q0+16w+16).
// LDS layouts XOR-chunk-swizzled: phys_chunk = logical_chunk ^ (row & 7).
// For all fragment reads row = X*16+lr, so (row&7)==(lr&7).
__global__ __launch_bounds__(256) void attn_kernel(const unsigned short* __restrict__ Qb,
                                                   const unsigned short* __restrict__ Kb,
                                                   const unsigned short* __restrict__ Vt,
                                                   unsigned short* __restrict__ AO) {
    __shared__ alignas(16) unsigned short K_lds[64 * 128];   // [key][dim], swizzled
    __shared__ alignas(16) unsigned short V_lds[128 * 64];   // [dim][key], swizzled
    __shared__ alignas(16) unsigned short P_lds[4][16 * 64]; // per-wave [qrow][key], swizzled

    const int tid = threadIdx.x;
    const int qt = (int)gridDim.x - 1 - (int)blockIdx.x;   // heavy blocks dispatch first
    const int h = blockIdx.y, b = blockIdx.z;
    const int kvh = h >> 2;
    const int q0 = qt * 64;
    const int w = tid >> 6, lane = tid & 63, lr = lane & 15, lg = lane >> 4;
    const int sw = lr & 7;   // swizzle key for this lane's fragment rows

    const unsigned short* Q  = Qb + (size_t)((b * 32 + h) * 2048) * 128;
    const unsigned short* Kp = Kb + (size_t)((b * 8 + kvh) * 2048) * 128;
    const unsigned short* Vp = Vt + (size_t)((b * 8 + kvh) * 128) * 2048;

    // Q a-frags: A[m=lane&15][k=quad*8+j], 4 frags cover k=0..127
    short8 qa[4];
#pragma unroll
    for (int f = 0; f < 4; ++f)
        qa[f] = *(const short8*)&Q[(q0 + w * 16 + lr) * 128 + f * 32 + lg * 8];

    short8 ones;
#pragma unroll
    for (int j = 0; j < 8; ++j) ones[j] = (short)0x3F80;   // bf16 1.0

    float m_i[4], l_i[4];
    floatx4 o[8];
#pragma unroll
    for (int r = 0; r < 4; ++r) { m_i[r] = -1e30f; l_i[r] = 0.f; }
#pragma unroll
    for (int dt = 0; dt < 8; ++dt) o[dt] = (floatx4){0.f, 0.f, 0.f, 0.f};

    for (int it = 0; it <= qt; ++it) {
        const int k0 = it * 64;
        __syncthreads();   // prior iteration's LDS readers done
#pragma unroll
        for (int i = 0; i < 4; ++i) {
            int c = i * 256 + tid;
            // K: 16 chunks/row; source column chunk = phys ^ (row&7)
            int krow = c >> 4, kcl = (c & 15) ^ (krow & 7);
            g2l16(&Kp[(size_t)(k0 + krow) * 128 + kcl * 8], &K_lds[c * 8]);
            // V: 8 chunks/row
            int vrow = c >> 3, vcl = (c & 7) ^ (vrow & 7);
            g2l16(&Vp[(size_t)vrow * 2048 + k0 + vcl * 8], &V_lds[c * 8]);
        }
        __syncthreads();   // staging visible

        // S = Q * K^T  (16 q-rows x 64 keys per wave), exp2 domain
        floatx4 s[4];
#pragma unroll
        for (int nt = 0; nt < 4; ++nt) s[nt] = (floatx4){0.f, 0.f, 0.f, 0.f};
#pragma unroll
        for (int nt = 0; nt < 4; ++nt)
#pragma unroll
            for (int f = 0; f < 4; ++f) {
                int cp = (f * 4 + lg) ^ sw;
                short8 kb = *(const short8*)&K_lds[(nt * 16 + lr) * 128 + cp * 8];
                s[nt] = __builtin_amdgcn_mfma_f32_16x16x32_bf16(qa[f], kb, s[nt], 0, 0, 0);
            }

        if (it == qt) {
            // diagonal tile: mask col_local > row_local
#pragma unroll
            for (int nt = 0; nt < 4; ++nt)
#pragma unroll
                for (int r = 0; r < 4; ++r)
                    if (nt * 16 + lr > w * 16 + lg * 4 + r) s[nt][r] = -1e30f;
        }

        // online softmax: row max (rows owned by 16-lane groups; reduce across lr)
        float mx[4];
#pragma unroll
        for (int r = 0; r < 4; ++r)
            mx[r] = fmaxf(fmaxf(s[0][r], s[1][r]), fmaxf(s[2][r], s[3][r]));
#pragma unroll
        for (int off = 1; off < 16; off <<= 1)
#pragma unroll
            for (int r = 0; r < 4; ++r)
                mx[r] = fmaxf(mx[r], __shfl_xor(mx[r], off, 64));

        float al[4], p[4][4];
#pragma unroll
        for (int r = 0; r < 4; ++r) {
            float mn = fmaxf(m_i[r], mx[r]);
            al[r] = __builtin_amdgcn_exp2f(m_i[r] - mn);
            m_i[r] = mn;
        }
#pragma unroll
        for (int nt = 0; nt < 4; ++nt)
#pragma unroll
            for (int r = 0; r < 4; ++r)
                p[nt][r] = __builtin_amdgcn_exp2f(s[nt][r] - m_i[r]);

        // P: C-layout -> LDS (swizzled [qrow][key], per-wave region)
#pragma unroll
        for (int nt = 0; nt < 4; ++nt)
#pragma unroll
            for (int r = 0; r < 4; ++r) {
                int col = nt * 16 + lr, row = lg * 4 + r;
                int cp = (col >> 3) ^ (row & 7);
                P_lds[w][row * 64 + cp * 8 + (col & 7)] = f2bf(p[nt][r]);
            }
        // wave-local RAW: writes committed before reads (lockstep issue + lgkmcnt drain)
        asm volatile("s_waitcnt lgkmcnt(0)" ::: "memory");

        short8 pa0 = *(const short8*)&P_lds[w][lr * 64 + ((0 * 4 + lg) ^ sw) * 8];
        short8 pa1 = *(const short8*)&P_lds[w][lr * 64 + ((1 * 4 + lg) ^ sw) * 8];

        // row-sum of P via ones-MFMA: every lane gets its rows' sums in C-layout
        floatx4 t = (floatx4){0.f, 0.f, 0.f, 0.f};
        t = __builtin_amdgcn_mfma_f32_16x16x32_bf16(pa0, ones, t, 0, 0, 0);
        t = __builtin_amdgcn_mfma_f32_16x16x32_bf16(pa1, ones, t, 0, 0, 0);

#pragma unroll
        for (int r = 0; r < 4; ++r) l_i[r] = l_i[r] * al[r] + t[r];
#pragma unroll
        for (int dt = 0; dt < 8; ++dt)
#pragma unroll
            for (int r = 0; r < 4; ++r) o[dt][r] *= al[r];

        // O += P * V
#pragma unroll
        for (int dt = 0; dt < 8; ++dt) {
            int cp = (0 * 4 + lg) ^ sw;
            short8 vb = *(const short8*)&V_lds[(dt * 16 + lr) * 64 + cp * 8];
            o[dt] = __builtin_amdgcn_mfma_f32_16x16x32_bf16(pa0, vb, o[dt], 0, 0, 0);
        }
#pragma unroll
        for (int dt = 0; dt < 8; ++dt) {
            int cp = (1 * 4 + lg) ^ sw;
            short8 vb = *(const short8*)&V_lds[(dt * 16 + lr) * 64 + cp * 8];
            o[dt] = __builtin_amdgcn_mfma_f32_16x16x32_bf16(pa1, vb, o[dt], 0, 0, 0);
        }
    }

    // epilogue: normalize, write AO[token][h*128+d] bf16
#pragma unroll
    for (int dt = 0; dt < 8; ++dt)
#pragma unroll
        for (int r = 0; r < 4; ++r) {
            int q = q0 + w * 16 + lg * 4 + r;
            AO[(size_t)(b * 2048 + q) * 4096 + h * 128 + dt * 16 + lr] = f2bf(o[dt][r] / l_i[r]);
        }
}

extern "C" void kernel_launch(void* const* d_in, const int* in_sizes, int n_in,
                              void* d_out, int out_size, void* d_ws, size_t ws_size,
                              hipStream_t stream) {
    const float* x  = (const float*)d_in[0];
    const float* wq = (const float*)d_in[1];
    const float* wk = (const float*)d_in[2];
    const float* wv = (const float*)d_in[3];
    const float* wo = (const float*)d_in[4];
    const float* fc = (const float*)d_in[5];
    const float* fs = (const float*)d_in[6];
    float* out = (float*)d_out;

    // ---- workspace layout (112 MB total) ----
    // [0, 50.3MB):      wqkvt   -- dead after gemm1, then reused as qb|kb|vt
    // [50.3, 83.9MB):   xb      -- dead after gemm1, then reused as ao
    // [83.9, 117.4MB):  wot
    // cqkv (bf16, 50.3MB) staged in d_out (67MB), consumed before final GEMM writes it.
    char* ws = (char*)d_ws;
    unsigned short* wqkvt = (unsigned short*)(ws);
    unsigned short* qb    = (unsigned short*)(ws);                      // alias wqkvt
    unsigned short* kb    = (unsigned short*)(ws + 33554432);           // alias wqkvt+33.5MB
    unsigned short* vt    = (unsigned short*)(ws + 41943040);           // alias wqkvt+41.9MB
    unsigned short* xb    = (unsigned short*)(ws + 50331648);
    unsigned short* ao    = xb;                                          // alias xb
    unsigned short* wot   = (unsigned short*)(ws + 83886080);
    unsigned short* cqkv  = (unsigned short*)d_out;                      // staging in d_out

    cast_x_kernel<<<16384, 256, 0, stream>>>(x, xb, 4194304);
    cast_transpose_kernel<<<dim3(64, 64), 256, 0, stream>>>(wq, wqkvt, 4096, 0);
    cast_transpose_kernel<<<dim3(16, 64), 256, 0, stream>>>(wk, wqkvt, 1024, 4096);
    cast_transpose_kernel<<<dim3(16, 64), 256, 0, stream>>>(wv, wqkvt, 1024, 5120);
    cast_transpose_kernel<<<dim3(64, 64), 256, 0, stream>>>(wo, wot, 4096, 0);

    // QKV GEMM: [4096,4096] x [6144,4096]^T -> cqkv bf16 (in d_out)
    gemm_bt_kernel<true><<<dim3(48, 32), 256, 0, stream>>>(xb, wqkvt, nullptr, cqkv, 4096, 6144, 4096);

    // RoPE + layouts (overwrite wqkvt region -- gemm1 already consumed it)
    rope_qk_kernel<<<dim3(10, 4096), 256, 0, stream>>>(cqkv, fc, fs, qb, kb);
    transpose_v_kernel<<<dim3(32, 8, 2), 256, 0, stream>>>(cqkv, vt);

    // attention -> ao (overwrites xb)
    attn_kernel<<<dim3(32, 32, 2), 256, 0, stream>>>(qb, kb, vt, ao);

    // output GEMM: [4096,4096] x [4096,4096]^T -> out fp32 (overwrites cqkv staging)
    gemm_bt_kernel<false><<<dim3(32, 32), 256, 0, stream>>>(ao, wot, out, nullptr, 4096, 4096, 4096);
}

// Round 4
// 953.378 us; speedup vs baseline: 1.2939x; 1.0573x over previous
//
#include <hip/hip_runtime.h>
#include <hip/hip_bf16.h>
#include <stdint.h>

// Problem constants: B=2, L=2048, D=4096, H=32, KVH=8, HD=128, REP=4
// Pipeline (all bf16 MFMA, fp32 accum):
//   cast x -> bf16; cast+transpose wq|wk|wv -> Wt[6144][4096]; wo -> Wot[4096][4096]
//   QKV GEMM (bf16 out, staged in d_out)
//   RoPE(Q,K) -> head-major bf16 (Q pre-scaled by log2(e)/sqrt(HD)); V -> transposed bf16
//   flash-style causal GQA attention (exp2 domain, XOR-swizzled LDS, 128-row q-blocks,
//     32 q-rows/wave, double-buffered K/V staging, 1 barrier/iter)
//   output GEMM (fp32 out -> d_out)

typedef __attribute__((ext_vector_type(8))) short short8;
typedef __attribute__((ext_vector_type(4))) float floatx4;

__device__ __forceinline__ unsigned short f2bf(float f) {
    union { float f; uint32_t u; } v; v.f = f;
    uint32_t u = v.u;
    return (unsigned short)((u + 0x7fffu + ((u >> 16) & 1u)) >> 16);
}

__device__ __forceinline__ float bf2f(unsigned short h) {
    union { uint32_t u; float f; } v; v.u = (uint32_t)h << 16; return v.f;
}

// Async global->LDS, 16B per lane. LDS dest must be wave-uniform base + lane*16.
__device__ __forceinline__ void g2l16(const void* g, void* l) {
    __builtin_amdgcn_global_load_lds(
        (__attribute__((address_space(1))) void*)g,
        (__attribute__((address_space(3))) void*)l,
        16, 0, 0);
}

// ---------------- cast x (fp32 -> bf16, row-major) ----------------
__global__ __launch_bounds__(256) void cast_x_kernel(const float* __restrict__ X,
                                                     unsigned short* __restrict__ Xb,
                                                     int n4) {
    int i = blockIdx.x * 256 + threadIdx.x;
    if (i < n4) {
        floatx4 v = *(const floatx4*)&X[i * 4];
        unsigned int p0 = (unsigned int)f2bf(v[0]) | ((unsigned int)f2bf(v[1]) << 16);
        unsigned int p1 = (unsigned int)f2bf(v[2]) | ((unsigned int)f2bf(v[3]) << 16);
        uint2 pv; pv.x = p0; pv.y = p1;
        *(uint2*)&Xb[i * 4] = pv;
    }
}

// ------------- cast+transpose weight: W[K=4096][N] fp32 -> Wt[rowoff+n][4096] bf16 -------------
__global__ __launch_bounds__(256) void cast_transpose_kernel(const float* __restrict__ W,
                                                             unsigned short* __restrict__ Wt,
                                                             int N, int rowoff) {
    __shared__ alignas(16) float T[64][65];
    int n0 = blockIdx.x * 64, k0 = blockIdx.y * 64;
    int tid = threadIdx.x;
#pragma unroll
    for (int i = 0; i < 16; ++i) {
        int idx = i * 256 + tid;
        int r = idx >> 6, c = idx & 63;   // r: k-dir, c: n-dir
        T[r][c] = W[(k0 + r) * N + n0 + c];
    }
    __syncthreads();
#pragma unroll
    for (int i = 0; i < 16; ++i) {
        int idx = i * 256 + tid;
        int rn = idx >> 6, ck = idx & 63;
        Wt[(size_t)(rowoff + n0 + rn) * 4096 + k0 + ck] = f2bf(T[ck][rn]);
    }
}

// ---------------- GEMM: C[M][N] = A[M][K] bf16 * Bt[N][K] bf16 ----------------
// 128x128 tile, BK=32, 256 threads (2x2 waves of 64x64), m97-style.
template<bool BF16OUT>
__global__ __launch_bounds__(256) void gemm_bt_kernel(const unsigned short* __restrict__ A,
                                                      const unsigned short* __restrict__ Bt,
                                                      float* __restrict__ Cf,
                                                      unsigned short* __restrict__ Cb,
                                                      int M, int N, int K) {
    __shared__ alignas(16) unsigned short As[128 * 32];
    __shared__ alignas(16) unsigned short Bs[128 * 32];
    const int tid = threadIdx.x;
    const int n0 = blockIdx.x * 128;
    const int m0 = blockIdx.y * 128;
    const int w = tid >> 6, lane = tid & 63, lr = lane & 15, lg = lane >> 4;
    const int wm = (w >> 1) * 64, wn = (w & 1) * 64;

    floatx4 acc[4][4];
#pragma unroll
    for (int i = 0; i < 4; ++i)
#pragma unroll
        for (int j = 0; j < 4; ++j)
            acc[i][j] = (floatx4){0.f, 0.f, 0.f, 0.f};

    const unsigned short* ag = A + (size_t)(m0 + (tid >> 2)) * K + (tid & 3) * 8;
    const unsigned short* bg = Bt + (size_t)(n0 + (tid >> 2)) * K + (tid & 3) * 8;
    const size_t half = (size_t)64 * K;

    for (int k0 = 0; k0 < K; k0 += 32) {
        __syncthreads();   // protect LDS from previous iteration's readers
        g2l16(ag + k0,        &As[tid * 8]);
        g2l16(ag + k0 + half, &As[2048 + tid * 8]);
        g2l16(bg + k0,        &Bs[tid * 8]);
        g2l16(bg + k0 + half, &Bs[2048 + tid * 8]);
        __syncthreads();   // compiler drains vmcnt before barrier

        short8 a[4], b[4];
#pragma unroll
        for (int mt = 0; mt < 4; ++mt)
            a[mt] = *(const short8*)&As[(wm + mt * 16 + lr) * 32 + lg * 8];
#pragma unroll
        for (int nt = 0; nt < 4; ++nt)
            b[nt] = *(const short8*)&Bs[(wn + nt * 16 + lr) * 32 + lg * 8];
#pragma unroll
        for (int mt = 0; mt < 4; ++mt)
#pragma unroll
            for (int nt = 0; nt < 4; ++nt)
                acc[mt][nt] = __builtin_amdgcn_mfma_f32_16x16x32_bf16(a[mt], b[nt], acc[mt][nt], 0, 0, 0);
    }

    // Epilogue: C/D layout row=(lane>>4)*4+reg, col=lane&15
#pragma unroll
    for (int mt = 0; mt < 4; ++mt)
#pragma unroll
        for (int nt = 0; nt < 4; ++nt)
#pragma unroll
            for (int r = 0; r < 4; ++r) {
                size_t idx = (size_t)(m0 + wm + mt * 16 + lg * 4 + r) * N + n0 + wn + nt * 16 + lr;
                if (BF16OUT) Cb[idx] = f2bf(acc[mt][nt][r]);
                else         Cf[idx] = acc[mt][nt][r];
            }
}

// ---------------- RoPE on Q and K slices of Cqkv (bf16) -> bf16 head-major layouts ----------------
// Q pre-scaled by log2(e)/sqrt(HD) so attention works in exp2 domain.
__global__ __launch_bounds__(256) void rope_qk_kernel(const unsigned short* __restrict__ Cqkv,
                                                      const float* __restrict__ fc,
                                                      const float* __restrict__ fs,
                                                      unsigned short* __restrict__ Qb,
                                                      unsigned short* __restrict__ Kb) {
    int e = blockIdx.x * 256 + threadIdx.x;   // 0..2559
    int t = blockIdx.y;                       // token
    int b = t >> 11, l = t & 2047;
    if (e < 2048) {
        int h = e >> 6, d2 = e & 63;
        unsigned int xv = *(const unsigned int*)&Cqkv[(size_t)t * 6144 + h * 128 + d2 * 2];
        float xr = bf2f((unsigned short)(xv & 0xffffu));
        float xi = bf2f((unsigned short)(xv >> 16));
        float c = fc[l * 64 + d2], s = fs[l * 64 + d2];
        const float sc = 1.4426950408889634f * 0.08838834764831845f;  // log2(e)/sqrt(128)
        float orr = (xr * c - xi * s) * sc;
        float oii = (xr * s + xi * c) * sc;
        unsigned int pack = (unsigned int)f2bf(orr) | ((unsigned int)f2bf(oii) << 16);
        *(unsigned int*)&Qb[(size_t)((b * 32 + h) * 2048 + l) * 128 + d2 * 2] = pack;
    } else {
        int e2 = e - 2048;
        int kvh = e2 >> 6, d2 = e2 & 63;
        unsigned int xv = *(const unsigned int*)&Cqkv[(size_t)t * 6144 + 4096 + kvh * 128 + d2 * 2];
        float xr = bf2f((unsigned short)(xv & 0xffffu));
        float xi = bf2f((unsigned short)(xv >> 16));
        float c = fc[l * 64 + d2], s = fs[l * 64 + d2];
        float orr = xr * c - xi * s;
        float oii = xr * s + xi * c;
        unsigned int pack = (unsigned int)f2bf(orr) | ((unsigned int)f2bf(oii) << 16);
        *(unsigned int*)&Kb[(size_t)((b * 8 + kvh) * 2048 + l) * 128 + d2 * 2] = pack;
    }
}

// ---------------- V slice of Cqkv (bf16) -> transposed bf16 Vt[b][kvh][128][2048] ----------------
__global__ __launch_bounds__(256) void transpose_v_kernel(const unsigned short* __restrict__ Cqkv,
                                                          unsigned short* __restrict__ Vt) {
    __shared__ unsigned short T[64][130];
    int l0 = blockIdx.x * 64;
    int kvh = blockIdx.y;
    int b = blockIdx.z;
    int tid = threadIdx.x;
#pragma unroll
    for (int i = 0; i < 32; ++i) {
        int idx = i * 256 + tid;
        int r = idx >> 7, c = idx & 127;
        T[r][c] = Cqkv[(size_t)(b * 2048 + l0 + r) * 6144 + 5120 + kvh * 128 + c];
    }
    __syncthreads();
#pragma unroll
    for (int i = 0; i < 32; ++i) {
        int idx = i * 256 + tid;
        int d = idx >> 6, lx = idx & 63;
        Vt[((size_t)(b * 8 + kvh) * 128 + d) * 2048 + l0 + lx] = T[lx][d];
    }
}

// ---------------- Flash-style causal attention ----------------
// grid (L/128, H, B), 256 threads = 4 waves. Wave w handles 32 q-rows
// [q0+32w, q0+32w+32) as two 16-row fragment sets. Key tiles of 64,
// double-buffered staging, ONE barrier per iteration.
// LDS XOR-chunk-swizzled: phys_chunk = logical_chunk ^ (row & 7); fragment
// rows are X*16+lr so the reader-side key is sw = lr&7.
__global__ __launch_bounds__(256, 2) void attn_kernel(const unsigned short* __restrict__ Qb,
                                                      const unsigned short* __restrict__ Kb,
                                                      const unsigned short* __restrict__ Vt,
                                                      unsigned short* __restrict__ AO) {
    __shared__ alignas(16) unsigned short K_lds[2][64 * 128];   // [buf][key][dim], swizzled
    __shared__ alignas(16) unsigned short V_lds[2][128 * 64];   // [buf][dim][key], swizzled
    __shared__ alignas(16) unsigned short P_lds[4][32 * 64];    // per-wave [qrow][key], swizzled

    const int tid = threadIdx.x;
    const int qt = (int)gridDim.x - 1 - (int)blockIdx.x;   // heavy blocks dispatch first
    const int h = blockIdx.y, b = blockIdx.z;
    const int kvh = h >> 2;
    const int q0 = qt * 128;
    const int w = tid >> 6, lane = tid & 63, lr = lane & 15, lg = lane >> 4;
    const int sw = lr & 7;
    const int wrow0 = q0 + w * 32;          // wave's first q-row
    const int wmax  = wrow0 + 31;           // wave's last q-row

    const unsigned short* Q  = Qb + (size_t)((b * 32 + h) * 2048) * 128;
    const unsigned short* Kp = Kb + (size_t)((b * 8 + kvh) * 2048) * 128;
    const unsigned short* Vp = Vt + (size_t)((b * 8 + kvh) * 128) * 2048;

    // Q a-frags for two 16-row sets: A[m=lr][k=lg*8+f*32..]
    short8 qa[2][4];
#pragma unroll
    for (int st = 0; st < 2; ++st)
#pragma unroll
        for (int f = 0; f < 4; ++f)
            qa[st][f] = *(const short8*)&Q[(wrow0 + st * 16 + lr) * 128 + f * 32 + lg * 8];

    short8 ones;
#pragma unroll
    for (int j = 0; j < 8; ++j) ones[j] = (short)0x3F80;   // bf16 1.0

    float m_i[2][4], l_i[2][4];
    floatx4 o[2][8];
#pragma unroll
    for (int st = 0; st < 2; ++st) {
#pragma unroll
        for (int r = 0; r < 4; ++r) { m_i[st][r] = -1e30f; l_i[st][r] = 0.f; }
#pragma unroll
        for (int dt = 0; dt < 8; ++dt) o[st][dt] = (floatx4){0.f, 0.f, 0.f, 0.f};
    }

    const int nIter = 2 * qt + 2;

    // stage key-tile `it` into buffer bufsel
#define STAGE(it_, bufsel_)                                                        \
    do {                                                                           \
        const int k0s = (it_) * 64;                                                \
        _Pragma("unroll")                                                          \
        for (int i = 0; i < 4; ++i) {                                              \
            int c = i * 256 + tid;                                                 \
            int krow = c >> 4, kcl = (c & 15) ^ (krow & 7);                        \
            g2l16(&Kp[(size_t)(k0s + krow) * 128 + kcl * 8], &K_lds[bufsel_][c * 8]); \
            int vrow = c >> 3, vcl = (c & 7) ^ (vrow & 7);                         \
            g2l16(&Vp[(size_t)vrow * 2048 + k0s + vcl * 8], &V_lds[bufsel_][c * 8]); \
        }                                                                          \
    } while (0)

    STAGE(0, 0);

    for (int it = 0; it < nIter; ++it) {
        const int k0 = it * 64;
        const int bsel = it & 1;
        __syncthreads();   // drains vmcnt: buf[bsel] ready; all waves done reading buf[bsel^1]
        if (it + 1 < nIter) STAGE(it + 1, bsel ^ 1);

        if (k0 > wmax) continue;   // fully-masked tile for this wave (wave-uniform)

        // S = Q * K^T : 2 row-sets x 64 keys; K fragment reused across both sets
        floatx4 s[2][4];
#pragma unroll
        for (int st = 0; st < 2; ++st)
#pragma unroll
            for (int nt = 0; nt < 4; ++nt) s[st][nt] = (floatx4){0.f, 0.f, 0.f, 0.f};
#pragma unroll
        for (int nt = 0; nt < 4; ++nt)
#pragma unroll
            for (int f = 0; f < 4; ++f) {
                int cp = (f * 4 + lg) ^ sw;
                short8 kbf = *(const short8*)&K_lds[bsel][(nt * 16 + lr) * 128 + cp * 8];
                s[0][nt] = __builtin_amdgcn_mfma_f32_16x16x32_bf16(qa[0][f], kbf, s[0][nt], 0, 0, 0);
                s[1][nt] = __builtin_amdgcn_mfma_f32_16x16x32_bf16(qa[1][f], kbf, s[1][nt], 0, 0, 0);
            }

        if (k0 + 63 > wrow0) {
            // tile overlaps diagonal: mask key > row
#pragma unroll
            for (int st = 0; st < 2; ++st)
#pragma unroll
                for (int nt = 0; nt < 4; ++nt)
#pragma unroll
                    for (int r = 0; r < 4; ++r)
                        if (k0 + nt * 16 + lr > wrow0 + st * 16 + lg * 4 + r)
                            s[st][nt][r] = -1e30f;
        }

        // online softmax per row-set (rows owned by 16-lane groups; reduce across lr)
        float mx[2][4], al[2][4];
#pragma unroll
        for (int st = 0; st < 2; ++st)
#pragma unroll
            for (int r = 0; r < 4; ++r)
                mx[st][r] = fmaxf(fmaxf(s[st][0][r], s[st][1][r]), fmaxf(s[st][2][r], s[st][3][r]));
#pragma unroll
        for (int off = 1; off < 16; off <<= 1)
#pragma unroll
            for (int st = 0; st < 2; ++st)
#pragma unroll
                for (int r = 0; r < 4; ++r)
                    mx[st][r] = fmaxf(mx[st][r], __shfl_xor(mx[st][r], off, 64));

#pragma unroll
        for (int st = 0; st < 2; ++st)
#pragma unroll
            for (int r = 0; r < 4; ++r) {
                float mn = fmaxf(m_i[st][r], mx[st][r]);
                al[st][r] = __builtin_amdgcn_exp2f(m_i[st][r] - mn);
                m_i[st][r] = mn;
            }

        // P = exp2(S - m) -> LDS (swizzled per-wave [qrow 0..31][key])
#pragma unroll
        for (int st = 0; st < 2; ++st)
#pragma unroll
            for (int nt = 0; nt < 4; ++nt)
#pragma unroll
                for (int r = 0; r < 4; ++r) {
                    float pv = __builtin_amdgcn_exp2f(s[st][nt][r] - m_i[st][r]);
                    int col = nt * 16 + lr, row = st * 16 + lg * 4 + r;
                    int cp = (col >> 3) ^ (row & 7);
                    P_lds[w][row * 64 + cp * 8 + (col & 7)] = f2bf(pv);
                }
        // wave-local RAW: DS ops in-order per wave; drain before fragment reads
        asm volatile("s_waitcnt lgkmcnt(0)" ::: "memory");

        short8 pa[2][2];
#pragma unroll
        for (int st = 0; st < 2; ++st)
#pragma unroll
            for (int kk = 0; kk < 2; ++kk)
                pa[st][kk] = *(const short8*)&P_lds[w][(st * 16 + lr) * 64 + ((kk * 4 + lg) ^ sw) * 8];

        // row-sums via ones-MFMA (C-layout result aligns with l_i)
#pragma unroll
        for (int st = 0; st < 2; ++st) {
            floatx4 t = (floatx4){0.f, 0.f, 0.f, 0.f};
            t = __builtin_amdgcn_mfma_f32_16x16x32_bf16(pa[st][0], ones, t, 0, 0, 0);
            t = __builtin_amdgcn_mfma_f32_16x16x32_bf16(pa[st][1], ones, t, 0, 0, 0);
#pragma unroll
            for (int r = 0; r < 4; ++r) l_i[st][r] = l_i[st][r] * al[st][r] + t[r];
#pragma unroll
            for (int dt = 0; dt < 8; ++dt)
#pragma unroll
                for (int r = 0; r < 4; ++r) o[st][dt][r] *= al[st][r];
        }

        // O += P * V ; V fragment reused across both row-sets
#pragma unroll
        for (int kk = 0; kk < 2; ++kk) {
            int cp = (kk * 4 + lg) ^ sw;
#pragma unroll
            for (int dt = 0; dt < 8; ++dt) {
                short8 vb = *(const short8*)&V_lds[bsel][(dt * 16 + lr) * 64 + cp * 8];
                o[0][dt] = __builtin_amdgcn_mfma_f32_16x16x32_bf16(pa[0][kk], vb, o[0][dt], 0, 0, 0);
                o[1][dt] = __builtin_amdgcn_mfma_f32_16x16x32_bf16(pa[1][kk], vb, o[1][dt], 0, 0, 0);
            }
        }
    }
#undef STAGE

    // epilogue: normalize, write AO[token][h*128+d] bf16
#pragma unroll
    for (int st = 0; st < 2; ++st)
#pragma unroll
        for (int dt = 0; dt < 8; ++dt)
#pragma unroll
            for (int r = 0; r < 4; ++r) {
                int q = wrow0 + st * 16 + lg * 4 + r;
                AO[(size_t)(b * 2048 + q) * 4096 + h * 128 + dt * 16 + lr] =
                    f2bf(o[st][dt][r] / l_i[st][r]);
            }
}

extern "C" void kernel_launch(void* const* d_in, const int* in_sizes, int n_in,
                              void* d_out, int out_size, void* d_ws, size_t ws_size,
                              hipStream_t stream) {
    const float* x  = (const float*)d_in[0];
    const float* wq = (const float*)d_in[1];
    const float* wk = (const float*)d_in[2];
    const float* wv = (const float*)d_in[3];
    const float* wo = (const float*)d_in[4];
    const float* fc = (const float*)d_in[5];
    const float* fs = (const float*)d_in[6];
    float* out = (float*)d_out;

    // ---- workspace layout (112 MB total) ----
    // [0, 50.3MB):      wqkvt   -- dead after gemm1, then reused as qb|kb|vt
    // [50.3, 83.9MB):   xb      -- dead after gemm1, then reused as ao
    // [83.9, 117.4MB):  wot
    // cqkv (bf16, 50.3MB) staged in d_out (67MB), consumed before final GEMM writes it.
    char* ws = (char*)d_ws;
    unsigned short* wqkvt = (unsigned short*)(ws);
    unsigned short* qb    = (unsigned short*)(ws);                      // alias wqkvt
    unsigned short* kb    = (unsigned short*)(ws + 33554432);           // alias wqkvt+33.5MB
    unsigned short* vt    = (unsigned short*)(ws + 41943040);           // alias wqkvt+41.9MB
    unsigned short* xb    = (unsigned short*)(ws + 50331648);
    unsigned short* ao    = xb;                                          // alias xb
    unsigned short* wot   = (unsigned short*)(ws + 83886080);
    unsigned short* cqkv  = (unsigned short*)d_out;                      // staging in d_out

    cast_x_kernel<<<16384, 256, 0, stream>>>(x, xb, 4194304);
    cast_transpose_kernel<<<dim3(64, 64), 256, 0, stream>>>(wq, wqkvt, 4096, 0);
    cast_transpose_kernel<<<dim3(16, 64), 256, 0, stream>>>(wk, wqkvt, 1024, 4096);
    cast_transpose_kernel<<<dim3(16, 64), 256, 0, stream>>>(wv, wqkvt, 1024, 5120);
    cast_transpose_kernel<<<dim3(64, 64), 256, 0, stream>>>(wo, wot, 4096, 0);

    // QKV GEMM: [4096,4096] x [6144,4096]^T -> cqkv bf16 (in d_out)
    gemm_bt_kernel<true><<<dim3(48, 32), 256, 0, stream>>>(xb, wqkvt, nullptr, cqkv, 4096, 6144, 4096);

    // RoPE + layouts (overwrite wqkvt region -- gemm1 already consumed it)
    rope_qk_kernel<<<dim3(10, 4096), 256, 0, stream>>>(cqkv, fc, fs, qb, kb);
    transpose_v_kernel<<<dim3(32, 8, 2), 256, 0, stream>>>(cqkv, vt);

    // attention -> ao (overwrites xb)
    attn_kernel<<<dim3(16, 32, 2), 256, 0, stream>>>(qb, kb, vt, ao);

    // output GEMM: [4096,4096] x [4096,4096]^T -> out fp32 (overwrites cqkv staging)
    gemm_bt_kernel<false><<<dim3(32, 32), 256, 0, stream>>>(ao, wot, out, nullptr, 4096, 4096, 4096);
}